// Round 5
// baseline (20368.941 us; speedup 1.0000x reference)
//
#include <hip/hip_runtime.h>
#include <stdint.h>

// HardLSTM R5: barrier-free step loop. Per-WAVE flags (80/group) gate the
// step; each wave publishes its own 64 h values (global_store_short, sc0 sc1)
// and its flag after staging x -> flags transitively sync intra-wg LDS reuse.
// h loads issued before x-half MFMA to hide L3 flight. No __syncthreads,
// no fences, no LDS h round-trip. 2 groups x 10 wgs x 512 thr.

#define T_STEPS 2000
#define BATCH   32
#define IDIM    320
#define HDIM    320
#define NWG     20
#define WPG     10
#define NTH     512
#define GB      16
#define UPW     32
#define LDK     324            // LDS row stride (elems): 648B -> conflict-free (R4 measured 0)
#define SSZ     (BATCH*HDIM)   // 10240 ushorts per h slot

typedef __attribute__((ext_vector_type(8))) short short8;
typedef __attribute__((ext_vector_type(4))) float f32x4;
typedef __attribute__((ext_vector_type(4))) unsigned short ushort4v;
typedef __attribute__((ext_vector_type(4))) unsigned int uint32x4;
typedef __attribute__((ext_vector_type(2))) unsigned int uint32x2;

static __device__ __forceinline__ unsigned short f2bf(float f) {
    uint32_t u = __float_as_uint(f);
    u += 0x7FFFu + ((u >> 16) & 1u);   // RTNE
    return (unsigned short)(u >> 16);
}
static __device__ __forceinline__ float bf2f(unsigned short s) {
    return __uint_as_float(((uint32_t)s) << 16);
}
static __device__ __forceinline__ float sat01(float v)  { return fminf(fmaxf(v, 0.f), 1.f); }
static __device__ __forceinline__ float clamp1(float v) { return fminf(fmaxf(v, -1.f), 1.f); }

static __device__ __forceinline__ void cvt_store(unsigned short* hi_p,
                                                 unsigned short* lo_p, float4 v) {
    ushort4v hi, lo;
    hi[0] = f2bf(v.x); lo[0] = f2bf(v.x - bf2f(hi[0]));
    hi[1] = f2bf(v.y); lo[1] = f2bf(v.y - bf2f(hi[1]));
    hi[2] = f2bf(v.z); lo[2] = f2bf(v.z - bf2f(hi[2]));
    hi[3] = f2bf(v.w); lo[3] = f2bf(v.w - bf2f(hi[3]));
    *(ushort4v*)hi_p = hi;
    *(ushort4v*)lo_p = lo;
}

__global__ __launch_bounds__(NTH, 2)
void hard_lstm(const float* __restrict__ x, const float* __restrict__ w_ih,
               const float* __restrict__ w_hh, const float* __restrict__ b_ih,
               const float* __restrict__ b_hh, float* __restrict__ out,
               unsigned short* __restrict__ hb, uint32_t* __restrict__ flags)
{
    __shared__ __align__(16) unsigned short xb[2][2][GB][LDK];  // [slot][hi/lo][b][k]

    const int tid  = threadIdx.x;
    const int wgg  = blockIdx.x;
    const int grp  = wgg / WPG;
    const int wgl  = wgg % WPG;
    const int wave = tid >> 6;
    const int lane = tid & 63;
    const int col  = lane & 15;    // MFMA A-row / B-col (batch within group)
    const int q    = lane >> 4;    // k-chunk / output row-quad

    // ---- A fragments (weights) -> registers, bf16 hi/lo, full K=640 ----
    short8 ahi[20], alo[20];
    {
        const int jA   = wgl * UPW + wave * 4 + (col >> 2);
        const int grow = (col & 3) * HDIM + jA;
        const float* wi = w_ih + (size_t)grow * IDIM;
        const float* wh = w_hh + (size_t)grow * HDIM;
        #pragma unroll
        for (int s = 0; s < 20; ++s) {
            #pragma unroll
            for (int jj = 0; jj < 8; ++jj) {
                int k = s * 32 + q * 8 + jj;
                float w = (k < IDIM) ? wi[k] : wh[k - IDIM];
                unsigned short hi = f2bf(w);
                ahi[s][jj] = (short)hi;
                alo[s][jj] = (short)f2bf(w - bf2f(hi));
            }
        }
    }

    const int jOut = wgl * UPW + wave * 4 + q;   // hidden unit owned by this lane
    const int bOut = grp * GB + col;             // global batch owned by this lane
    float bias4[4];
    #pragma unroll
    for (int v = 0; v < 4; ++v)
        bias4[v] = b_ih[v * HDIM + jOut] + b_hh[v * HDIM + jOut];

    // staging chunks: 1280 float4 over [16][320]; thread owns c0,c1(,c2)
    const int c0 = tid, c1 = tid + NTH, c2 = tid + 2 * NTH;
    const int b0 = c0 / 80, k0 = (c0 % 80) * 4;
    const int b1 = c1 / 80, k1 = (c1 % 80) * 4;
    const int b2 = c2 / 80, k2 = (c2 % 80) * 4;
    const bool has2 = (tid < 256);

    uint32_t* fbase = flags + grp * 128;          // 80 flags (+pad) per group
    uint32_t* fself = fbase + (wgl * 8 + wave);
    const int pl = (lane < 40) ? lane : 39;
    const uint32_t* fpoll = fbase + 2 * pl;

    unsigned short* hSelf = hb + (size_t)bOut * HDIM + jOut;       // + slot*SSZ
    const unsigned short* hLoad = hb + (size_t)bOut * HDIM + q * 8; // + slot*SSZ

    // ---------- pre-loop: h(0)=0 own elem, stage x(0), flag=1 ----------
    asm volatile("global_store_short %0, %1, off sc0 sc1"
                 :: "v"(hSelf), "v"(0u) : "memory");
    {
        const float4* xs = (const float4*)(x + (size_t)(grp * GB) * IDIM);
        float4 v0 = xs[c0], v1 = xs[c1], v2 = {};
        if (has2) v2 = xs[c2];
        cvt_store(&xb[0][0][b0][k0], &xb[0][1][b0][k0], v0);
        cvt_store(&xb[0][0][b1][k1], &xb[0][1][b1][k1], v1);
        if (has2) cvt_store(&xb[0][0][b2][k2], &xb[0][1][b2][k2], v2);
    }
    asm volatile("s_waitcnt vmcnt(0) lgkmcnt(0)" ::: "memory");
    asm volatile("global_store_dword %0, %1, off sc0 sc1"
                 :: "v"(fself), "v"(1u) : "memory");

    float c_state = 0.f;

    #pragma unroll 1
    for (int t = 0; t < T_STEPS; ++t) {
        const int slot  = t & 1;
        const int slotn = slot ^ 1;

        // ---- x(t+1) prefetch into regs (cached path) ----
        float4 xr0 = {}, xr1 = {}, xr2 = {};
        const bool havex = (t + 1 < T_STEPS);
        if (havex) {
            const float4* xs = (const float4*)(x + ((size_t)(t + 1) * BATCH + grp * GB) * IDIM);
            xr0 = xs[c0]; xr1 = xs[c1];
            if (has2) xr2 = xs[c2];
        }

        // ---- poll all 80 wave-flags of this group >= t+1 ----
        {
            const uint32_t tgt = (uint32_t)(t + 1);
            uint32x2 fv;
            do {
                asm volatile("global_load_dwordx2 %0, %1, off sc0 sc1\n\t"
                             "s_waitcnt vmcnt(0)"
                             : "=&v"(fv) : "v"(fpoll) : "memory");
            } while (!__all((int)(fv[0] >= tgt && fv[1] >= tgt)));
        }

        // ---- issue h(t) B-fragment loads (no wait yet) ----
        uint32x4 hv[10];
        {
            const unsigned short* hp = hLoad + (size_t)slot * SSZ;
            asm volatile(
                "global_load_dwordx4 %0, %10, off sc0 sc1\n\t"
                "global_load_dwordx4 %1, %10, off offset:64 sc0 sc1\n\t"
                "global_load_dwordx4 %2, %10, off offset:128 sc0 sc1\n\t"
                "global_load_dwordx4 %3, %10, off offset:192 sc0 sc1\n\t"
                "global_load_dwordx4 %4, %10, off offset:256 sc0 sc1\n\t"
                "global_load_dwordx4 %5, %10, off offset:320 sc0 sc1\n\t"
                "global_load_dwordx4 %6, %10, off offset:384 sc0 sc1\n\t"
                "global_load_dwordx4 %7, %10, off offset:448 sc0 sc1\n\t"
                "global_load_dwordx4 %8, %10, off offset:512 sc0 sc1\n\t"
                "global_load_dwordx4 %9, %10, off offset:576 sc0 sc1"
                : "=&v"(hv[0]), "=&v"(hv[1]), "=&v"(hv[2]), "=&v"(hv[3]), "=&v"(hv[4]),
                  "=&v"(hv[5]), "=&v"(hv[6]), "=&v"(hv[7]), "=&v"(hv[8]), "=&v"(hv[9])
                : "v"(hp) : "memory");
        }

        // ---- x-half MFMA (30) while h loads are in flight ----
        f32x4 acc0 = {0.f, 0.f, 0.f, 0.f};
        f32x4 acc1 = {0.f, 0.f, 0.f, 0.f};
        f32x4 acc2 = {0.f, 0.f, 0.f, 0.f};
        {
            const unsigned short* bxh = &xb[slot][0][col][q * 8];
            const unsigned short* bxl = &xb[slot][1][col][q * 8];
            #pragma unroll
            for (int s = 0; s < 10; ++s) {
                short8 bh = *(const short8*)(bxh + s * 32);
                short8 bl = *(const short8*)(bxl + s * 32);
                acc0 = __builtin_amdgcn_mfma_f32_16x16x32_bf16(ahi[s], bh, acc0, 0, 0, 0);
                acc1 = __builtin_amdgcn_mfma_f32_16x16x32_bf16(alo[s], bh, acc1, 0, 0, 0);
                acc2 = __builtin_amdgcn_mfma_f32_16x16x32_bf16(ahi[s], bl, acc2, 0, 0, 0);
            }
        }

        // ---- wait h data, fence scheduler (rule #18), h-half MFMA (20) ----
        asm volatile("s_waitcnt vmcnt(0)" ::: "memory");
        __builtin_amdgcn_sched_barrier(0);
        #pragma unroll
        for (int s = 0; s < 10; ++s) {
            short8 bh = *(const short8*)&hv[s];
            acc0 = __builtin_amdgcn_mfma_f32_16x16x32_bf16(ahi[10 + s], bh, acc0, 0, 0, 0);
            acc1 = __builtin_amdgcn_mfma_f32_16x16x32_bf16(alo[10 + s], bh, acc1, 0, 0, 0);
        }

        // ---- gate math ----
        float p[4];
        #pragma unroll
        for (int v = 0; v < 4; ++v) p[v] = acc0[v] + acc1[v] + acc2[v] + bias4[v];
        float gi = sat01(0.2f * p[0] + 0.5f);
        float gf = sat01(0.2f * p[1] + 0.5f);
        float gg = clamp1(p[2]);
        float go = sat01(0.2f * p[3] + 0.5f);
        c_state = gf * c_state + gi * gg;
        float h1 = go * clamp1(c_state);

        // ---- publish h(t+1) (own ushort), out, stage x(t+1); then drain+flag ----
        asm volatile("global_store_short %0, %1, off sc0 sc1"
                     :: "v"(hSelf + (size_t)slotn * SSZ),
                        "v"((uint32_t)f2bf(h1)) : "memory");
        out[(size_t)t * SSZ + (size_t)bOut * HDIM + jOut] = h1;
        if (havex) {
            cvt_store(&xb[slotn][0][b0][k0], &xb[slotn][1][b0][k0], xr0);
            cvt_store(&xb[slotn][0][b1][k1], &xb[slotn][1][b1][k1], xr1);
            if (has2) cvt_store(&xb[slotn][0][b2][k2], &xb[slotn][1][b2][k2], xr2);
        }
        asm volatile("s_waitcnt vmcnt(0) lgkmcnt(0)" ::: "memory");
        asm volatile("global_store_dword %0, %1, off sc0 sc1"
                     :: "v"(fself), "v"((uint32_t)(t + 2)) : "memory");
    }
}

extern "C" void kernel_launch(void* const* d_in, const int* in_sizes, int n_in,
                              void* d_out, int out_size, void* d_ws, size_t ws_size,
                              hipStream_t stream) {
    const float* x   = (const float*)d_in[0];
    const float* wih = (const float*)d_in[1];
    const float* whh = (const float*)d_in[2];
    const float* bih = (const float*)d_in[3];
    const float* bhh = (const float*)d_in[4];
    float* out = (float*)d_out;

    unsigned short* hb = (unsigned short*)d_ws;                    // 2*SSZ ushorts = 40 KiB
    uint32_t* flags = (uint32_t*)((char*)d_ws + (size_t)2 * SSZ * 2);  // 2 groups x 128 dwords

    hipMemsetAsync(flags, 0, 2 * 128 * sizeof(uint32_t), stream);

    void* args[] = {(void*)&x, (void*)&wih, (void*)&whh, (void*)&bih, (void*)&bhh,
                    (void*)&out, (void*)&hb, (void*)&flags};
    hipError_t e = hipLaunchCooperativeKernel((const void*)hard_lstm, dim3(NWG), dim3(NTH),
                                              args, 0, stream);
    if (e != hipSuccess) {
        hipLaunchKernelGGL(hard_lstm, dim3(NWG), dim3(NTH), 0, stream,
                           x, wih, whh, bih, bhh, out, hb, flags);
    }
}

// Round 6
// 17477.390 us; speedup vs baseline: 1.1654x; 1.1654x over previous
//
#include <hip/hip_runtime.h>
#include <stdint.h>

// HardLSTM R6: R3's protocol (coalesced wave0 publish + per-wg flags) with
// three serial bubbles removed: (1) all-wave flag poll -> one barrier/step,
// (2) h loads issued before x-half MFMAs (latency hidden under compute),
// (3) own wg's h fragment taken from LDS, own flag skipped in poll.
// 2 groups x 10 wgs x 512 thr; full K=640 weights in regs (bf16 hi/lo).

#define T_STEPS 2000
#define BATCH   32
#define IDIM    320
#define HDIM    320
#define NWG     20
#define WPG     10
#define NTH     512
#define GB      16
#define UPW     32
#define LDK     324            // x-LDS row stride: R4 measured 0 bank conflicts
#define H1P     36             // h1s row stride (pad to break gather conflicts)
#define SSZ     (BATCH*HDIM)   // 10240 ushorts per h slot

typedef __attribute__((ext_vector_type(8))) short short8;
typedef __attribute__((ext_vector_type(4))) float f32x4;
typedef __attribute__((ext_vector_type(4))) unsigned short ushort4v;
typedef __attribute__((ext_vector_type(4))) unsigned int uint32x4;

static __device__ __forceinline__ unsigned short f2bf(float f) {
    uint32_t u = __float_as_uint(f);
    u += 0x7FFFu + ((u >> 16) & 1u);   // RTNE
    return (unsigned short)(u >> 16);
}
static __device__ __forceinline__ float bf2f(unsigned short s) {
    return __uint_as_float(((uint32_t)s) << 16);
}
static __device__ __forceinline__ float sat01(float v)  { return fminf(fmaxf(v, 0.f), 1.f); }
static __device__ __forceinline__ float clamp1(float v) { return fminf(fmaxf(v, -1.f), 1.f); }

static __device__ __forceinline__ void cvt_store(unsigned short* hi_p,
                                                 unsigned short* lo_p, float4 v) {
    ushort4v hi, lo;
    hi[0] = f2bf(v.x); lo[0] = f2bf(v.x - bf2f(hi[0]));
    hi[1] = f2bf(v.y); lo[1] = f2bf(v.y - bf2f(hi[1]));
    hi[2] = f2bf(v.z); lo[2] = f2bf(v.z - bf2f(hi[2]));
    hi[3] = f2bf(v.w); lo[3] = f2bf(v.w - bf2f(hi[3]));
    *(ushort4v*)hi_p = hi;
    *(ushort4v*)lo_p = lo;
}

__global__ __launch_bounds__(NTH, 2)
void hard_lstm(const float* __restrict__ x, const float* __restrict__ w_ih,
               const float* __restrict__ w_hh, const float* __restrict__ b_ih,
               const float* __restrict__ b_hh, float* __restrict__ out,
               unsigned short* __restrict__ hb, uint32_t* __restrict__ flags)
{
    __shared__ __align__(16) unsigned short xb[2][2][GB][LDK];  // [slot][hi/lo][b][k]
    __shared__ __align__(16) unsigned short h1s[2][GB][H1P];    // own wg h, bf16

    const int tid  = threadIdx.x;
    const int wgg  = blockIdx.x;
    const int grp  = wgg / WPG;
    const int wgl  = wgg % WPG;
    const int wave = tid >> 6;
    const int lane = tid & 63;
    const int col  = lane & 15;    // MFMA A-row / B-col (batch within group)
    const int q    = lane >> 4;    // k-chunk / output row-quad

    // ---- A fragments (weights) -> registers, bf16 hi/lo, full K=640 ----
    short8 ahi[20], alo[20];
    {
        const int jA   = wgl * UPW + wave * 4 + (col >> 2);
        const int grow = (col & 3) * HDIM + jA;
        const float* wi = w_ih + (size_t)grow * IDIM;
        const float* wh = w_hh + (size_t)grow * HDIM;
        #pragma unroll
        for (int s = 0; s < 20; ++s) {
            #pragma unroll
            for (int jj = 0; jj < 8; ++jj) {
                int k = s * 32 + q * 8 + jj;
                float w = (k < IDIM) ? wi[k] : wh[k - IDIM];
                unsigned short hi = f2bf(w);
                ahi[s][jj] = (short)hi;
                alo[s][jj] = (short)f2bf(w - bf2f(hi));
            }
        }
    }

    const int jOut = wgl * UPW + wave * 4 + q;   // hidden unit owned by this lane
    const int bOut = grp * GB + col;             // global batch owned by this lane
    float bias4[4];
    #pragma unroll
    for (int v = 0; v < 4; ++v)
        bias4[v] = b_ih[v * HDIM + jOut] + b_hh[v * HDIM + jOut];

    // staging chunks (1280 float4 over [16][320]); waves 4-7 take the 3rd chunk
    const int c0 = tid, c1 = tid + NTH;
    const int c2 = 1024 + (tid - 256);
    const int b0 = c0 / 80, k0 = (c0 % 80) * 4;
    const int b1 = c1 / 80, k1 = (c1 % 80) * 4;
    const int b2g = (tid >= 256) ? c2 : c0;
    const int b2 = b2g / 80, k2 = (b2g % 80) * 4;
    const bool has2 = (tid >= 256);

    uint32_t* fbase = flags + grp * 16;          // group's 10 flags in one line
    const int  pl    = (lane < WPG) ? lane : 0;
    const bool skipf = (lane >= WPG) || (pl == wgl);
    const uint32_t* fp = fbase + pl;

    unsigned short* hSelf = hb + (size_t)bOut * HDIM + jOut;        // + slot*SSZ
    const unsigned short* hLoad = hb + (size_t)bOut * HDIM + q * 8; // + slot*SSZ

    // ---------- pre-loop: h(0)=0 (LDS + global slot0), stage x(0), flag=1 ----------
    h1s[1][col][wave * 4 + q] = 0;
    asm volatile("global_store_short %0, %1, off sc0 sc1"
                 :: "v"(hSelf), "v"(0u) : "memory");
    {
        const float4* xs = (const float4*)(x + (size_t)(grp * GB) * IDIM);
        float4 v0 = xs[c0], v1 = xs[c1], v2 = {};
        if (has2) v2 = xs[c2];
        cvt_store(&xb[0][0][b0][k0], &xb[0][1][b0][k0], v0);
        cvt_store(&xb[0][0][b1][k1], &xb[0][1][b1][k1], v1);
        if (has2) cvt_store(&xb[0][0][b2][k2], &xb[0][1][b2][k2], v2);
    }
    __syncthreads();   // drains each wave's VMEM before barrier
    if (tid == 0)
        asm volatile("global_store_dword %0, %1, off sc0 sc1"
                     :: "v"(fbase + wgl), "v"(1u) : "memory");

    float c_state = 0.f;

    #pragma unroll 1
    for (int t = 0; t < T_STEPS; ++t) {
        const int slot  = t & 1;
        const int slotn = slot ^ 1;

        // ---- x(t+1) prefetch into regs (cached path; drained by poll) ----
        float4 xr0 = {}, xr1 = {}, xr2 = {};
        const bool havex = (t + 1 < T_STEPS);
        if (havex) {
            const float4* xs = (const float4*)(x + ((size_t)(t + 1) * BATCH + grp * GB) * IDIM);
            xr0 = xs[c0]; xr1 = xs[c1];
            if (has2) xr2 = xs[c2];
        }

        // ---- all-wave poll: 9 remote wg flags >= t+1 (own wg skipped) ----
        {
            const uint32_t tgt = (uint32_t)(t + 1);
            uint32_t v;
            do {
                asm volatile("global_load_dword %0, %1, off sc0 sc1\n\t"
                             "s_waitcnt vmcnt(0)"
                             : "=&v"(v) : "v"(fp) : "memory");
                if (skipf) v = tgt;
            } while (!__all((int)(v >= tgt)));
        }

        // ---- issue h(t) remote fragments (no wait); own fragment from LDS ----
        uint32x4 hv[10];
        {
            const unsigned short* hp = hLoad + (size_t)slot * SSZ;
            asm volatile(
                "global_load_dwordx4 %0, %10, off sc0 sc1\n\t"
                "global_load_dwordx4 %1, %10, off offset:64 sc0 sc1\n\t"
                "global_load_dwordx4 %2, %10, off offset:128 sc0 sc1\n\t"
                "global_load_dwordx4 %3, %10, off offset:192 sc0 sc1\n\t"
                "global_load_dwordx4 %4, %10, off offset:256 sc0 sc1\n\t"
                "global_load_dwordx4 %5, %10, off offset:320 sc0 sc1\n\t"
                "global_load_dwordx4 %6, %10, off offset:384 sc0 sc1\n\t"
                "global_load_dwordx4 %7, %10, off offset:448 sc0 sc1\n\t"
                "global_load_dwordx4 %8, %10, off offset:512 sc0 sc1\n\t"
                "global_load_dwordx4 %9, %10, off offset:576 sc0 sc1"
                : "=&v"(hv[0]), "=&v"(hv[1]), "=&v"(hv[2]), "=&v"(hv[3]), "=&v"(hv[4]),
                  "=&v"(hv[5]), "=&v"(hv[6]), "=&v"(hv[7]), "=&v"(hv[8]), "=&v"(hv[9])
                : "v"(hp) : "memory");
        }
        short8 hvown = *(const short8*)&h1s[slotn][col][q * 8];  // own wg's h(t)

        // ---- x-half MFMA (30) while h loads are in flight ----
        f32x4 acc0 = {0.f, 0.f, 0.f, 0.f};
        f32x4 acc1 = {0.f, 0.f, 0.f, 0.f};
        f32x4 acc2 = {0.f, 0.f, 0.f, 0.f};
        {
            const unsigned short* bxh = &xb[slot][0][col][q * 8];
            const unsigned short* bxl = &xb[slot][1][col][q * 8];
            #pragma unroll
            for (int s = 0; s < 10; ++s) {
                short8 bh = *(const short8*)(bxh + s * 32);
                short8 bl = *(const short8*)(bxl + s * 32);
                acc0 = __builtin_amdgcn_mfma_f32_16x16x32_bf16(ahi[s], bh, acc0, 0, 0, 0);
                acc1 = __builtin_amdgcn_mfma_f32_16x16x32_bf16(alo[s], bh, acc1, 0, 0, 0);
                acc2 = __builtin_amdgcn_mfma_f32_16x16x32_bf16(ahi[s], bl, acc2, 0, 0, 0);
            }
        }

        // ---- wait remote h, fence scheduler (rule #18), h-half MFMA (20) ----
        asm volatile("s_waitcnt vmcnt(0)" ::: "memory");
        __builtin_amdgcn_sched_barrier(0);
        #pragma unroll
        for (int s = 0; s < 10; ++s) {
            short8 bh = (s == wgl) ? hvown : *(const short8*)&hv[s];
            acc0 = __builtin_amdgcn_mfma_f32_16x16x32_bf16(ahi[10 + s], bh, acc0, 0, 0, 0);
            acc1 = __builtin_amdgcn_mfma_f32_16x16x32_bf16(alo[10 + s], bh, acc1, 0, 0, 0);
        }

        // ---- gate math: lane owns (bOut, jOut) ----
        float p[4];
        #pragma unroll
        for (int v = 0; v < 4; ++v) p[v] = acc0[v] + acc1[v] + acc2[v] + bias4[v];
        float gi = sat01(0.2f * p[0] + 0.5f);
        float gf = sat01(0.2f * p[1] + 0.5f);
        float gg = clamp1(p[2]);
        float go = sat01(0.2f * p[3] + 0.5f);
        c_state = gf * c_state + gi * gg;
        float h1 = go * clamp1(c_state);

        // ---- local updates: h1 -> LDS, x(t+1) -> LDS, out -> global ----
        h1s[slot][col][wave * 4 + q] = f2bf(h1);
        if (havex) {
            cvt_store(&xb[slotn][0][b0][k0], &xb[slotn][1][b0][k0], xr0);
            cvt_store(&xb[slotn][0][b1][k1], &xb[slotn][1][b1][k1], xr1);
            if (has2) cvt_store(&xb[slotn][0][b2][k2], &xb[slotn][1][b2][k2], xr2);
        }
        out[(size_t)t * SSZ + (size_t)bOut * HDIM + jOut] = h1;

        __syncthreads();   // h1s/xb ready; single barrier per step

        // ---- wave0: coalesced publish h(t+1) + flag (R3's proven path) ----
        if (wave == 0) {
            const int b = lane >> 2, part = lane & 3;
            uint32x4 d = *(const uint32x4*)&h1s[slot][b][part * 8];
            unsigned short* dst = hb + (size_t)slotn * SSZ
                                + (size_t)(grp * GB + b) * HDIM + wgl * UPW + part * 8;
            asm volatile("global_store_dwordx4 %0, %1, off sc0 sc1\n\t"
                         "s_waitcnt vmcnt(0)" :: "v"(dst), "v"(d) : "memory");
            if (lane == 0)
                asm volatile("global_store_dword %0, %1, off sc0 sc1"
                             :: "v"(fbase + wgl), "v"((uint32_t)(t + 2)) : "memory");
        }
    }
}

extern "C" void kernel_launch(void* const* d_in, const int* in_sizes, int n_in,
                              void* d_out, int out_size, void* d_ws, size_t ws_size,
                              hipStream_t stream) {
    const float* x   = (const float*)d_in[0];
    const float* wih = (const float*)d_in[1];
    const float* whh = (const float*)d_in[2];
    const float* bih = (const float*)d_in[3];
    const float* bhh = (const float*)d_in[4];
    float* out = (float*)d_out;

    unsigned short* hb = (unsigned short*)d_ws;                        // 2*SSZ ushorts
    uint32_t* flags = (uint32_t*)((char*)d_ws + (size_t)2 * SSZ * 2);  // 2 x 16 dwords

    hipMemsetAsync(flags, 0, 2 * 16 * sizeof(uint32_t), stream);

    void* args[] = {(void*)&x, (void*)&wih, (void*)&whh, (void*)&bih, (void*)&bhh,
                    (void*)&out, (void*)&hb, (void*)&flags};
    hipError_t e = hipLaunchCooperativeKernel((const void*)hard_lstm, dim3(NWG), dim3(NTH),
                                              args, 0, stream);
    if (e != hipSuccess) {
        hipLaunchKernelGGL(hard_lstm, dim3(NWG), dim3(NTH), 0, stream,
                           x, wih, whh, bih, bhh, out, hb, flags);
    }
}

// Round 7
// 17139.587 us; speedup vs baseline: 1.1884x; 1.0197x over previous
//
#include <hip/hip_runtime.h>
#include <stdint.h>

// HardLSTM R7: R3's proven protocol (wave0 poll + coalesced wave0 publish +
// per-wg flags) with HBM stalls removed from the serial chain:
//  - wave0 does no x staging -> its poll vmcnt(0) is clean
//  - x loads issued at step END, cvt'd to LDS at next step START (latency
//    overlaps publish+poll window)
//  - raw s_barrier with lgkmcnt-only drains (no vmcnt drain at barriers)
// 2 groups x 10 wgs x 512 thr; full K=640 weights in regs (bf16 hi/lo).

#define T_STEPS 2000
#define BATCH   32
#define IDIM    320
#define HDIM    320
#define NWG     20
#define WPG     10
#define NTH     512
#define GB      16
#define UPW     32
#define LDK     324            // x-LDS row stride (648B): R4/R6 measured ~0 conflicts
#define H1P     36             // h1s row stride
#define SSZ     (BATCH*HDIM)   // 10240 ushorts per h slot

typedef __attribute__((ext_vector_type(8))) short short8;
typedef __attribute__((ext_vector_type(4))) float f32x4;
typedef __attribute__((ext_vector_type(4))) unsigned short ushort4v;
typedef __attribute__((ext_vector_type(4))) unsigned int uint32x4;

static __device__ __forceinline__ unsigned short f2bf(float f) {
    uint32_t u = __float_as_uint(f);
    u += 0x7FFFu + ((u >> 16) & 1u);   // RTNE
    return (unsigned short)(u >> 16);
}
static __device__ __forceinline__ float bf2f(unsigned short s) {
    return __uint_as_float(((uint32_t)s) << 16);
}
static __device__ __forceinline__ float sat01(float v)  { return fminf(fmaxf(v, 0.f), 1.f); }
static __device__ __forceinline__ float clamp1(float v) { return fminf(fmaxf(v, -1.f), 1.f); }

static __device__ __forceinline__ void cvt_store(unsigned short* hi_p,
                                                 unsigned short* lo_p, float4 v) {
    ushort4v hi, lo;
    hi[0] = f2bf(v.x); lo[0] = f2bf(v.x - bf2f(hi[0]));
    hi[1] = f2bf(v.y); lo[1] = f2bf(v.y - bf2f(hi[1]));
    hi[2] = f2bf(v.z); lo[2] = f2bf(v.z - bf2f(hi[2]));
    hi[3] = f2bf(v.w); lo[3] = f2bf(v.w - bf2f(hi[3]));
    *(ushort4v*)hi_p = hi;
    *(ushort4v*)lo_p = lo;
}

// barriers that do NOT drain VMEM (keep x loads / publish acks in flight)
static __device__ __forceinline__ void bar_none() {
    asm volatile("" ::: "memory");
    __builtin_amdgcn_s_barrier();
    __builtin_amdgcn_sched_barrier(0);
}
static __device__ __forceinline__ void bar_lds() {
    asm volatile("s_waitcnt lgkmcnt(0)" ::: "memory");
    __builtin_amdgcn_s_barrier();
    __builtin_amdgcn_sched_barrier(0);
}

__global__ __launch_bounds__(NTH, 2)
void hard_lstm(const float* __restrict__ x, const float* __restrict__ w_ih,
               const float* __restrict__ w_hh, const float* __restrict__ b_ih,
               const float* __restrict__ b_hh, float* __restrict__ out,
               unsigned short* __restrict__ hb, uint32_t* __restrict__ flags)
{
    __shared__ __align__(16) unsigned short xb[2][GB][LDK];  // [hi/lo][b][k] single-buf
    __shared__ __align__(16) unsigned short h1s[GB][H1P];    // own wg h1, bf16

    const int tid  = threadIdx.x;
    const int wgg  = blockIdx.x;
    const int grp  = wgg / WPG;
    const int wgl  = wgg % WPG;
    const int wave = tid >> 6;
    const int lane = tid & 63;
    const int col  = lane & 15;    // MFMA A-row / B-col (batch within group)
    const int q    = lane >> 4;    // k-chunk / output row-quad

    // ---- A fragments (weights) -> registers, bf16 hi/lo, full K=640 ----
    short8 ahi[20], alo[20];
    {
        const int jA   = wgl * UPW + wave * 4 + (col >> 2);
        const int grow = (col & 3) * HDIM + jA;
        const float* wi = w_ih + (size_t)grow * IDIM;
        const float* wh = w_hh + (size_t)grow * HDIM;
        #pragma unroll
        for (int s = 0; s < 20; ++s) {
            #pragma unroll
            for (int jj = 0; jj < 8; ++jj) {
                int k = s * 32 + q * 8 + jj;
                float w = (k < IDIM) ? wi[k] : wh[k - IDIM];
                unsigned short hi = f2bf(w);
                ahi[s][jj] = (short)hi;
                alo[s][jj] = (short)f2bf(w - bf2f(hi));
            }
        }
    }

    const int jOut = wgl * UPW + wave * 4 + q;   // hidden unit owned by this lane
    const int bOut = grp * GB + col;             // global batch owned by this lane
    float bias4[4];
    #pragma unroll
    for (int v = 0; v < 4; ++v)
        bias4[v] = b_ih[v * HDIM + jOut] + b_hh[v * HDIM + jOut];

    // x staging: waves 1-7 only (448 threads x 3 chunks >= 1280 float4)
    const bool stg  = (tid >= 64);
    const int  sidx = stg ? (tid - 64) : 0;
    const int  c0 = sidx, c1 = sidx + 448, c2 = (sidx < 384) ? sidx + 896 : sidx;
    const bool has2 = stg && (sidx < 384);
    const int  b0 = c0 / 80, k0 = (c0 % 80) * 4;
    const int  b1 = c1 / 80, k1 = (c1 % 80) * 4;
    const int  b2 = c2 / 80, k2 = (c2 % 80) * 4;

    uint32_t* fbase = flags + grp * 16;          // group's 10 flags in one line

    unsigned short* hSelf = hb + (size_t)bOut * HDIM + jOut;        // + slot*SSZ
    const unsigned short* hLoad = hb + (size_t)bOut * HDIM + q * 8; // + slot*SSZ

    // ---------- pre-loop: h(0)=0 in slot0, x(0) into regs, flag=1 ----------
    asm volatile("global_store_short %0, %1, off sc0 sc1"
                 :: "v"(hSelf), "v"(0u) : "memory");
    float4 xr0 = {}, xr1 = {}, xr2 = {};
    {
        const float4* xs = (const float4*)(x + (size_t)(grp * GB) * IDIM);
        if (stg) { xr0 = xs[c0]; xr1 = xs[c1]; if (has2) xr2 = xs[c2]; }
    }
    __syncthreads();   // full drain once (pre-loop only)
    if (tid == 0)
        asm volatile("global_store_dword %0, %1, off sc0 sc1"
                     :: "v"(fbase + wgl), "v"(1u) : "memory");

    float c_state = 0.f;

    #pragma unroll 1
    for (int t = 0; t < T_STEPS; ++t) {
        const int slot  = t & 1;
        const int slotn = slot ^ 1;

        // ---- (a) wave0 poll: 10 lanes, skip own flag ----
        if (wave == 0) {
            const uint32_t tgt = (uint32_t)(t + 1);
            const int  pl   = (lane < WPG) ? lane : 0;
            const bool skip = (lane >= WPG) || (pl == wgl);
            const uint32_t* fp = fbase + pl;
            uint32_t v;
            do {
                asm volatile("global_load_dword %0, %1, off sc0 sc1\n\t"
                             "s_waitcnt vmcnt(0)"
                             : "=&v"(v) : "v"(fp) : "memory");
                if (skip) v = tgt;
            } while (!__all((int)(v >= tgt)));
        }
        bar_none();   // (B) step release

        // ---- (b) cvt x(t) regs -> LDS (waves 1-7; compiler waits x loads) ----
        if (stg) {
            cvt_store(&xb[0][b0][k0], &xb[1][b0][k0], xr0);
            cvt_store(&xb[0][b1][k1], &xb[1][b1][k1], xr1);
            if (has2) cvt_store(&xb[0][b2][k2], &xb[1][b2][k2], xr2);
        }

        // ---- (c) issue h(t) fragment loads (no wait) ----
        uint32x4 hv[10];
        {
            const unsigned short* hp = hLoad + (size_t)slot * SSZ;
            asm volatile(
                "global_load_dwordx4 %0, %10, off sc0 sc1\n\t"
                "global_load_dwordx4 %1, %10, off offset:64 sc0 sc1\n\t"
                "global_load_dwordx4 %2, %10, off offset:128 sc0 sc1\n\t"
                "global_load_dwordx4 %3, %10, off offset:192 sc0 sc1\n\t"
                "global_load_dwordx4 %4, %10, off offset:256 sc0 sc1\n\t"
                "global_load_dwordx4 %5, %10, off offset:320 sc0 sc1\n\t"
                "global_load_dwordx4 %6, %10, off offset:384 sc0 sc1\n\t"
                "global_load_dwordx4 %7, %10, off offset:448 sc0 sc1\n\t"
                "global_load_dwordx4 %8, %10, off offset:512 sc0 sc1\n\t"
                "global_load_dwordx4 %9, %10, off offset:576 sc0 sc1"
                : "=&v"(hv[0]), "=&v"(hv[1]), "=&v"(hv[2]), "=&v"(hv[3]), "=&v"(hv[4]),
                  "=&v"(hv[5]), "=&v"(hv[6]), "=&v"(hv[7]), "=&v"(hv[8]), "=&v"(hv[9])
                : "v"(hp) : "memory");
        }

        bar_lds();    // (C) x tile visible to all waves

        // ---- (d) x-half MFMA (30) while h loads fly ----
        f32x4 acc0 = {0.f, 0.f, 0.f, 0.f};
        f32x4 acc1 = {0.f, 0.f, 0.f, 0.f};
        f32x4 acc2 = {0.f, 0.f, 0.f, 0.f};
        {
            const unsigned short* bxh = &xb[0][col][q * 8];
            const unsigned short* bxl = &xb[1][col][q * 8];
            #pragma unroll
            for (int s = 0; s < 10; ++s) {
                short8 bh = *(const short8*)(bxh + s * 32);
                short8 bl = *(const short8*)(bxl + s * 32);
                acc0 = __builtin_amdgcn_mfma_f32_16x16x32_bf16(ahi[s], bh, acc0, 0, 0, 0);
                acc1 = __builtin_amdgcn_mfma_f32_16x16x32_bf16(alo[s], bh, acc1, 0, 0, 0);
                acc2 = __builtin_amdgcn_mfma_f32_16x16x32_bf16(ahi[s], bl, acc2, 0, 0, 0);
            }
        }

        // ---- (e) wait h, fence (rule #18), h-half MFMA (20) ----
        asm volatile("s_waitcnt vmcnt(0)" ::: "memory");
        __builtin_amdgcn_sched_barrier(0);
        #pragma unroll
        for (int s = 0; s < 10; ++s) {
            short8 bh = *(const short8*)&hv[s];
            acc0 = __builtin_amdgcn_mfma_f32_16x16x32_bf16(ahi[10 + s], bh, acc0, 0, 0, 0);
            acc1 = __builtin_amdgcn_mfma_f32_16x16x32_bf16(alo[10 + s], bh, acc1, 0, 0, 0);
        }

        // ---- (f) gate math ----
        float p[4];
        #pragma unroll
        for (int v = 0; v < 4; ++v) p[v] = acc0[v] + acc1[v] + acc2[v] + bias4[v];
        float gi = sat01(0.2f * p[0] + 0.5f);
        float gf = sat01(0.2f * p[1] + 0.5f);
        float gg = clamp1(p[2]);
        float go = sat01(0.2f * p[3] + 0.5f);
        c_state = gf * c_state + gi * gg;
        float h1 = go * clamp1(c_state);

        // ---- (g) local: h1 -> LDS; issue x(t+1) loads; out store ----
        h1s[col][wave * 4 + q] = f2bf(h1);
        if (stg && (t + 1 < T_STEPS)) {
            const float4* xs = (const float4*)(x + ((size_t)(t + 1) * BATCH + grp * GB) * IDIM);
            xr0 = xs[c0]; xr1 = xs[c1];
            if (has2) xr2 = xs[c2];
        }
        out[(size_t)t * SSZ + (size_t)bOut * HDIM + jOut] = h1;

        bar_lds();    // (A) h1s ready; x loads stay in flight

        // ---- (h) wave0: coalesced publish h(t+1) + flag ----
        if (wave == 0) {
            const int b = lane >> 2, part = lane & 3;
            uint32x4 d = *(const uint32x4*)&h1s[b][part * 8];
            unsigned short* dst = hb + (size_t)slotn * SSZ
                                + (size_t)(grp * GB + b) * HDIM + wgl * UPW + part * 8;
            asm volatile("global_store_dwordx4 %0, %1, off sc0 sc1\n\t"
                         "s_waitcnt vmcnt(0)" :: "v"(dst), "v"(d) : "memory");
            if (lane == 0)
                asm volatile("global_store_dword %0, %1, off sc0 sc1"
                             :: "v"(fbase + wgl), "v"((uint32_t)(t + 2)) : "memory");
        }
    }
}

extern "C" void kernel_launch(void* const* d_in, const int* in_sizes, int n_in,
                              void* d_out, int out_size, void* d_ws, size_t ws_size,
                              hipStream_t stream) {
    const float* x   = (const float*)d_in[0];
    const float* wih = (const float*)d_in[1];
    const float* whh = (const float*)d_in[2];
    const float* bih = (const float*)d_in[3];
    const float* bhh = (const float*)d_in[4];
    float* out = (float*)d_out;

    unsigned short* hb = (unsigned short*)d_ws;                        // 2*SSZ ushorts
    uint32_t* flags = (uint32_t*)((char*)d_ws + (size_t)2 * SSZ * 2);  // 2 x 16 dwords

    hipMemsetAsync(flags, 0, 2 * 16 * sizeof(uint32_t), stream);

    void* args[] = {(void*)&x, (void*)&wih, (void*)&whh, (void*)&bih, (void*)&bhh,
                    (void*)&out, (void*)&hb, (void*)&flags};
    hipError_t e = hipLaunchCooperativeKernel((const void*)hard_lstm, dim3(NWG), dim3(NTH),
                                              args, 0, stream);
    if (e != hipSuccess) {
        hipLaunchKernelGGL(hard_lstm, dim3(NWG), dim3(NTH), 0, stream,
                           x, wih, whh, bih, bhh, out, hb, flags);
    }
}

// Round 8
// 14072.273 us; speedup vs baseline: 1.4475x; 1.2180x over previous
//
#include <hip/hip_runtime.h>
#include <stdint.h>

// HardLSTM R8 = R3 (proven 9.27ms anchor) + one change: x(t+1) load/cvt and
// out store moved AFTER the pre-publish barrier, so their HBM latency/acks
// overlap the publish+flag+poll window instead of being drained at the
// barrier. Wave0 exempt from staging (clean poll). LDK 328->324 (0-conflict).
// Protocol identical to R3: wave0 poll (AGENT atomic), blocking h-load asm,
// 50-MFMA block, coalesced wave0 publish (sc0 sc1) + per-wg flag.

#define T_STEPS 2000
#define BATCH   32
#define IDIM    320
#define HDIM    320
#define NWG     20
#define WPG     10
#define NTH     512
#define GB      16
#define UPW     32
#define LDK     324            // 648B row stride: R4/R6 measured ~0 bank conflicts
#define SSZ     (BATCH*HDIM)   // 10240 ushorts per h slot

typedef __attribute__((ext_vector_type(8))) short short8;
typedef __attribute__((ext_vector_type(4))) float f32x4;
typedef __attribute__((ext_vector_type(4))) unsigned short ushort4v;
typedef __attribute__((ext_vector_type(4))) unsigned int uint32x4;

static __device__ __forceinline__ unsigned short f2bf(float f) {
    uint32_t u = __float_as_uint(f);
    u += 0x7FFFu + ((u >> 16) & 1u);   // RTNE
    return (unsigned short)(u >> 16);
}
static __device__ __forceinline__ float bf2f(unsigned short s) {
    return __uint_as_float(((uint32_t)s) << 16);
}
static __device__ __forceinline__ float sat01(float v)  { return fminf(fmaxf(v, 0.f), 1.f); }
static __device__ __forceinline__ float clamp1(float v) { return fminf(fmaxf(v, -1.f), 1.f); }

static __device__ __forceinline__ void cvt_store(unsigned short* hi_p,
                                                 unsigned short* lo_p, float4 v) {
    ushort4v hi, lo;
    hi[0] = f2bf(v.x); lo[0] = f2bf(v.x - bf2f(hi[0]));
    hi[1] = f2bf(v.y); lo[1] = f2bf(v.y - bf2f(hi[1]));
    hi[2] = f2bf(v.z); lo[2] = f2bf(v.z - bf2f(hi[2]));
    hi[3] = f2bf(v.w); lo[3] = f2bf(v.w - bf2f(hi[3]));
    *(ushort4v*)hi_p = hi;
    *(ushort4v*)lo_p = lo;
}

__global__ __launch_bounds__(NTH, 2)
void hard_lstm(const float* __restrict__ x, const float* __restrict__ w_ih,
               const float* __restrict__ w_hh, const float* __restrict__ b_ih,
               const float* __restrict__ b_hh, float* __restrict__ out,
               unsigned short* __restrict__ hb, uint32_t* __restrict__ flags)
{
    __shared__ __align__(16) unsigned short xb[2][2][GB][LDK];  // [slot][hi/lo][b][k]
    __shared__ __align__(16) unsigned short h1s[2][GB][UPW];    // bf16 h1 scratch

    const int tid  = threadIdx.x;
    const int wgg  = blockIdx.x;
    const int grp  = wgg / WPG;
    const int wgl  = wgg % WPG;
    const int wave = tid >> 6;
    const int lane = tid & 63;
    const int col  = lane & 15;    // MFMA A-row / B-col (batch within group)
    const int q    = lane >> 4;    // k-chunk / output row-quad

    // ---- A fragments (weights) -> registers, bf16 hi/lo, full K=640 ----
    short8 ahi[20], alo[20];
    {
        const int jA   = wgl * UPW + wave * 4 + (col >> 2);
        const int grow = (col & 3) * HDIM + jA;
        const float* wi = w_ih + (size_t)grow * IDIM;
        const float* wh = w_hh + (size_t)grow * HDIM;
        #pragma unroll
        for (int s = 0; s < 20; ++s) {
            #pragma unroll
            for (int jj = 0; jj < 8; ++jj) {
                int k = s * 32 + q * 8 + jj;
                float w = (k < IDIM) ? wi[k] : wh[k - IDIM];
                unsigned short hi = f2bf(w);
                ahi[s][jj] = (short)hi;
                alo[s][jj] = (short)f2bf(w - bf2f(hi));
            }
        }
    }

    const int jOut = wgl * UPW + wave * 4 + q;   // hidden unit owned by this lane
    const int bOut = grp * GB + col;             // global batch owned by this lane
    float bias4[4];
    #pragma unroll
    for (int v = 0; v < 4; ++v)
        bias4[v] = b_ih[v * HDIM + jOut] + b_hh[v * HDIM + jOut];

    // x staging: waves 1-7 only (448 thr x 3 chunks covers 1280 float4)
    const bool stg  = (tid >= 64);
    const int  sidx = stg ? (tid - 64) : 0;
    const int  c0 = sidx, c1 = sidx + 448, c2 = (sidx < 384) ? sidx + 896 : sidx;
    const bool has2 = stg && (sidx < 384);
    const int  b0 = c0 / 80, k0 = (c0 % 80) * 4;
    const int  b1 = c1 / 80, k1 = (c1 % 80) * 4;
    const int  b2 = c2 / 80, k2 = (c2 % 80) * 4;

    uint32_t* fline = flags + grp * 16;          // group's flag cacheline
    uint32_t* fpoll = &fline[lane % WPG];

    // h-fragment base (batch col, k-offset q*8), per slot
    const unsigned short* hp0 = hb + (size_t)bOut * HDIM + q * 8;

    // ---------- pre-loop: h(0)=0 via publish path, stage x(0), flag=1 ----------
    h1s[1][col][wave * 4 + q] = 0;
    if (stg) {
        const float4* xs = (const float4*)(x + (size_t)(grp * GB) * IDIM);
        float4 v0 = xs[c0], v1 = xs[c1], v2 = {};
        if (has2) v2 = xs[c2];
        cvt_store(&xb[0][0][b0][k0], &xb[0][1][b0][k0], v0);
        cvt_store(&xb[0][0][b1][k1], &xb[0][1][b1][k1], v1);
        if (has2) cvt_store(&xb[0][0][b2][k2], &xb[0][1][b2][k2], v2);
    }
    __syncthreads();
    if (wave == 0) {
        const int b = lane >> 2, part = lane & 3;
        uint32x4 d = *(const uint32x4*)&h1s[1][b][part * 8];
        unsigned short* dst = hb + (size_t)(grp * GB + b) * HDIM + wgl * UPW + part * 8;
        asm volatile("global_store_dwordx4 %0, %1, off sc0 sc1\n\t"
                     "s_waitcnt vmcnt(0)" :: "v"(dst), "v"(d) : "memory");
        if (lane == 0)
            __hip_atomic_store(&fline[wgl], 1u, __ATOMIC_RELAXED, __HIP_MEMORY_SCOPE_SYSTEM);
    }

    float c_state = 0.f;

    #pragma unroll 1
    for (int t = 0; t < T_STEPS; ++t) {
        const int slot  = t & 1;
        const int slotn = slot ^ 1;

        // ---- poll: all 10 producer flags of this group >= t+1 (wave0) ----
        if (wave == 0) {
            const uint32_t tgt = (uint32_t)(t + 1);
            while (true) {
                uint32_t v = __hip_atomic_load(fpoll, __ATOMIC_RELAXED,
                                               __HIP_MEMORY_SCOPE_AGENT);
                if (__all((int)(v >= tgt))) break;
            }
        }
        __syncthreads();   // (B) step released; xb[slot] writes from t-1 visible

        // ---- h(t) B-fragments: 10x dwordx4, L3-coherent, blocking ----
        uint32x4 hv[10];
        {
            const unsigned short* hp = hp0 + (size_t)slot * SSZ;
            asm volatile(
                "global_load_dwordx4 %0, %10, off sc0 sc1\n\t"
                "global_load_dwordx4 %1, %10, off offset:64 sc0 sc1\n\t"
                "global_load_dwordx4 %2, %10, off offset:128 sc0 sc1\n\t"
                "global_load_dwordx4 %3, %10, off offset:192 sc0 sc1\n\t"
                "global_load_dwordx4 %4, %10, off offset:256 sc0 sc1\n\t"
                "global_load_dwordx4 %5, %10, off offset:320 sc0 sc1\n\t"
                "global_load_dwordx4 %6, %10, off offset:384 sc0 sc1\n\t"
                "global_load_dwordx4 %7, %10, off offset:448 sc0 sc1\n\t"
                "global_load_dwordx4 %8, %10, off offset:512 sc0 sc1\n\t"
                "global_load_dwordx4 %9, %10, off offset:576 sc0 sc1\n\t"
                "s_waitcnt vmcnt(0)"
                : "=&v"(hv[0]), "=&v"(hv[1]), "=&v"(hv[2]), "=&v"(hv[3]), "=&v"(hv[4]),
                  "=&v"(hv[5]), "=&v"(hv[6]), "=&v"(hv[7]), "=&v"(hv[8]), "=&v"(hv[9])
                : "v"(hp) : "memory");
        }

        // ---- MFMA: x-half 3-term (s=0..9), h-half 2-term (s=10..19) ----
        f32x4 acc0 = {0.f, 0.f, 0.f, 0.f};
        f32x4 acc1 = {0.f, 0.f, 0.f, 0.f};
        f32x4 acc2 = {0.f, 0.f, 0.f, 0.f};
        {
            const unsigned short* bxh = &xb[slot][0][col][q * 8];
            const unsigned short* bxl = &xb[slot][1][col][q * 8];
            #pragma unroll
            for (int s = 0; s < 10; ++s) {
                short8 bh = *(const short8*)(bxh + s * 32);
                short8 bl = *(const short8*)(bxl + s * 32);
                acc0 = __builtin_amdgcn_mfma_f32_16x16x32_bf16(ahi[s], bh, acc0, 0, 0, 0);
                acc1 = __builtin_amdgcn_mfma_f32_16x16x32_bf16(alo[s], bh, acc1, 0, 0, 0);
                acc2 = __builtin_amdgcn_mfma_f32_16x16x32_bf16(ahi[s], bl, acc2, 0, 0, 0);
            }
            #pragma unroll
            for (int s = 0; s < 10; ++s) {
                short8 bh = *(const short8*)&hv[s];
                acc0 = __builtin_amdgcn_mfma_f32_16x16x32_bf16(ahi[10 + s], bh, acc0, 0, 0, 0);
                acc1 = __builtin_amdgcn_mfma_f32_16x16x32_bf16(alo[10 + s], bh, acc1, 0, 0, 0);
            }
        }

        // ---- gate math ----
        float p[4];
        #pragma unroll
        for (int v = 0; v < 4; ++v) p[v] = acc0[v] + acc1[v] + acc2[v] + bias4[v];
        float gi = sat01(0.2f * p[0] + 0.5f);
        float gf = sat01(0.2f * p[1] + 0.5f);
        float gg = clamp1(p[2]);
        float go = sat01(0.2f * p[3] + 0.5f);
        c_state = gf * c_state + gi * gg;
        float h1 = go * clamp1(c_state);

        // h1 (bf16) -> LDS for wave0's coalesced publish
        h1s[slot][col][wave * 4 + q] = f2bf(h1);

        __syncthreads();   // (A) h1s ready; nothing heavy outstanding

        // ---- wave0: coalesced publish h(t+1) + flag (R3's proven path) ----
        if (wave == 0) {
            const int b = lane >> 2, part = lane & 3;
            uint32x4 d = *(const uint32x4*)&h1s[slot][b][part * 8];
            unsigned short* dst = hb + (size_t)slotn * SSZ
                                + (size_t)(grp * GB + b) * HDIM + wgl * UPW + part * 8;
            asm volatile("global_store_dwordx4 %0, %1, off sc0 sc1\n\t"
                         "s_waitcnt vmcnt(0)" :: "v"(dst), "v"(d) : "memory");
            if (lane == 0)
                __hip_atomic_store(&fline[wgl], (uint32_t)(t + 2), __ATOMIC_RELAXED,
                                   __HIP_MEMORY_SCOPE_SYSTEM);
        }

        // ---- overlapped with publish+poll: out store, x(t+1) load+cvt ----
        out[(size_t)t * SSZ + (size_t)bOut * HDIM + jOut] = h1;
        if (stg && (t + 1 < T_STEPS)) {
            const float4* xs = (const float4*)(x + ((size_t)(t + 1) * BATCH + grp * GB) * IDIM);
            float4 v0 = xs[c0], v1 = xs[c1], v2 = {};
            if (has2) v2 = xs[c2];
            cvt_store(&xb[slotn][0][b0][k0], &xb[slotn][1][b0][k0], v0);
            cvt_store(&xb[slotn][0][b1][k1], &xb[slotn][1][b1][k1], v1);
            if (has2) cvt_store(&xb[slotn][0][b2][k2], &xb[slotn][1][b2][k2], v2);
        }
        // acks/LDS writes drain at each wave's entry to barrier (B) of t+1,
        // which overlaps wave0's poll.
    }
}

extern "C" void kernel_launch(void* const* d_in, const int* in_sizes, int n_in,
                              void* d_out, int out_size, void* d_ws, size_t ws_size,
                              hipStream_t stream) {
    const float* x   = (const float*)d_in[0];
    const float* wih = (const float*)d_in[1];
    const float* whh = (const float*)d_in[2];
    const float* bih = (const float*)d_in[3];
    const float* bhh = (const float*)d_in[4];
    float* out = (float*)d_out;

    unsigned short* hb = (unsigned short*)d_ws;                        // 2*SSZ ushorts
    uint32_t* flags = (uint32_t*)((char*)d_ws + (size_t)2 * SSZ * 2);  // 2 x 16 dwords

    hipMemsetAsync(flags, 0, 2 * 16 * sizeof(uint32_t), stream);

    void* args[] = {(void*)&x, (void*)&wih, (void*)&whh, (void*)&bih, (void*)&bhh,
                    (void*)&out, (void*)&hb, (void*)&flags};
    hipError_t e = hipLaunchCooperativeKernel((const void*)hard_lstm, dim3(NWG), dim3(NTH),
                                              args, 0, stream);
    if (e != hipSuccess) {
        hipLaunchKernelGGL(hard_lstm, dim3(NWG), dim3(NTH), 0, stream,
                           x, wih, whh, bih, bhh, out, hb, flags);
    }
}